// Round 22
// baseline (196.890 us; speedup 1.0000x reference)
//
#include <hip/hip_runtime.h>
#include <hip/hip_bf16.h>
#include <math.h>

#define B_    2
#define L_    2048
#define E_    1024
#define H_    16
#define DH_   64
#define HID_  4096
#define NROW_ (B_*L_)   // 4096
#define BH_   (B_*H_)   // 32

// 0.125 (1/sqrt(DH)) * log2(e): Q pre-scale so P = exp2(S')
#define QSCL  0.18033688011112042f

typedef __attribute__((ext_vector_type(8)))  short    short8v;
typedef _Float16 half8v __attribute__((ext_vector_type(8)));
typedef __attribute__((ext_vector_type(16))) float    f32x16;

#define MFMA32(A, Bv, C) __builtin_amdgcn_mfma_f32_32x32x16_bf16((A), (Bv), (C), 0, 0, 0)
#define MFMAH(A, Bv, C)  __builtin_amdgcn_mfma_f32_32x32x16_f16((A), (Bv), (C), 0, 0, 0)

#define WAITV(N) asm volatile("s_waitcnt vmcnt(" #N ")" ::: "memory")
#define SBAR()   __builtin_amdgcn_s_barrier()

// float->bf16 round-half-up (2 ops).
__device__ __forceinline__ unsigned short f2bf(float f) {
    union { float f; unsigned u; } v; v.f = f;
    return (unsigned short)((v.u + 0x8000u) >> 16);
}
// pack two floats -> {bf16(hi), bf16(lo)} in 3 VALU ops via v_perm_b32
__device__ __forceinline__ unsigned pack2_bf16(float lo, float hi) {
    union { float f; unsigned u; } a, b; a.f = lo; b.f = hi;
    return __builtin_amdgcn_perm(b.u + 0x8000u, a.u + 0x8000u, 0x07060302u);
}
__device__ __forceinline__ float bf2f(unsigned short u) {
    union { unsigned u; float f; } v; v.u = ((unsigned)u) << 16;
    return v.f;
}

// async global->LDS, 16B per lane. Dest is wave-uniform base + lane*16.
__device__ __forceinline__ void gl_lds16(const void* g, void* l) {
    __builtin_amdgcn_global_load_lds(
        (const __attribute__((address_space(1))) unsigned int*)g,
        (__attribute__((address_space(3))) unsigned int*)l, 16, 0, 0);
}

// Abramowitz-Stegun 7.1.26, |abs err| < 1.5e-7
__device__ __forceinline__ float erf_fast(float v) {
    float a = fabsf(v);
    float t = __builtin_amdgcn_rcpf(1.0f + 0.3275911f * a);
    float p = t * (0.254829592f + t * (-0.284496736f + t * (1.421413741f +
              t * (-1.453152027f + t * 1.061405429f))));
    float r = 1.0f - p * __expf(-a * a);
    return copysignf(r, v);
}

// ---------------------------------------------------------------------------
// Kernel 0 (FUSED PREPS): one dispatch covering
//   blocks [0,2048):     zh = fp16(z)                     (no LDS)
//   blocks [2048,2816):  Tq/Tk/Tv = transpose+cast W*     (LDS tile)
//   blocks [2816,3840):  W1t = transpose+cast W1          (LDS tile)
// ---------------------------------------------------------------------------
__global__ __launch_bounds__(256) void prep_all(
    const float* __restrict__ z, _Float16* __restrict__ zh,
    const float* __restrict__ Wq, const float* __restrict__ Wk,
    const float* __restrict__ Wv,
    _Float16* __restrict__ Tq, _Float16* __restrict__ Tk,
    _Float16* __restrict__ Tv,
    const float* __restrict__ W1, _Float16* __restrict__ W1t)
{
    __shared__ float tile[64][65];
    const int blk = blockIdx.x;
    const int t   = threadIdx.x;

    if (blk < 2048) {
        const size_t i = ((size_t)blk * 256 + t) * 8;
        float4 a = *(const float4*)&z[i];
        float4 b = *(const float4*)&z[i + 4];
        union { _Float16 h[8]; half8v v; } o;
        o.h[0] = (_Float16)a.x; o.h[1] = (_Float16)a.y;
        o.h[2] = (_Float16)a.z; o.h[3] = (_Float16)a.w;
        o.h[4] = (_Float16)b.x; o.h[5] = (_Float16)b.y;
        o.h[6] = (_Float16)b.z; o.h[7] = (_Float16)b.w;
        *(half8v*)&zh[i] = o.v;
        return;
    }

    const float* src;
    _Float16*    dst;
    int r0, c0, ldd;
    if (blk < 2816) {
        int idx   = blk - 2048;
        int which = idx >> 8;
        int rem   = idx & 255;
        int bx    = rem & 15, by = rem >> 4;
        src = (which == 0) ? Wq : (which == 1) ? Wk : Wv;
        dst = (which == 0) ? Tq : (which == 1) ? Tk : Tv;
        r0 = by * 64; c0 = bx * 64; ldd = E_;
        #pragma unroll
        for (int u = 0; u < 4; ++u) {
            int f = t + 256 * u, row = f >> 4, c4 = (f & 15) << 2;
            *(float4*)&tile[row][c4] = *(const float4*)&src[(size_t)(r0 + row) * E_ + c0 + c4];
        }
    } else {
        int idx = blk - 2816;
        int bx  = idx & 63, by = idx >> 6;
        src = W1; dst = W1t;
        r0 = by * 64; c0 = bx * 64; ldd = E_;
        #pragma unroll
        for (int u = 0; u < 4; ++u) {
            int f = t + 256 * u, row = f >> 4, c4 = (f & 15) << 2;
            *(float4*)&tile[row][c4] = *(const float4*)&src[(size_t)(r0 + row) * HID_ + c0 + c4];
        }
    }
    __syncthreads();
    #pragma unroll
    for (int u = 0; u < 4; ++u) {
        int f = t + 256 * u, c = f >> 4, r4 = (f & 15) << 2;
        union { _Float16 h[4]; uint2 u2; } pk;
        pk.h[0] = (_Float16)tile[r4 + 0][c];
        pk.h[1] = (_Float16)tile[r4 + 1][c];
        pk.h[2] = (_Float16)tile[r4 + 2][c];
        pk.h[3] = (_Float16)tile[r4 + 3][c];
        *(uint2*)&dst[(size_t)(c0 + c) * ldd + r0 + r4] = pk.u2;
    }
}

// ---------------------------------------------------------------------------
// Kernel 1: fused QKV projection, fp16 MFMA, 128x128 tile, BK=64, 4 waves.
// Min-2-phase pipeline: one barrier per K-step. (R19-proven)
// ---------------------------------------------------------------------------
__global__ __launch_bounds__(256) void qkv_mfma(
    const _Float16* __restrict__ zh,
    const _Float16* __restrict__ Tall,      // fused [3072][1024]
    const float* __restrict__ bq, const float* __restrict__ bk,
    const float* __restrict__ bv,
    unsigned short* __restrict__ outQKV)    // Qb | Kb | Vb contiguous
{
    const int which = blockIdx.x >> 3;      // 1024/128 = 8 tiles per weight
    const float* bias = (which == 0) ? bq : (which == 1) ? bk : bv;
    const float  osc  = (which == 0) ? QSCL : 1.0f;
    unsigned short* out = outQKV + (size_t)which * ((size_t)BH_ * L_ * DH_);

    __shared__ _Float16 Ah[2][128 * 64];
    __shared__ _Float16 Bs[2][128 * 64];

    const int t    = threadIdx.x;
    const int lane = t & 63;
    const int w    = t >> 6;
    const int l31  = lane & 31;
    const int hq   = lane >> 5;
    const int wm   = w >> 1, wn = w & 1;
    const int m0   = blockIdx.y * 128;
    const int n0   = blockIdx.x * 128;      // global fused n

    const int srow0 = (lane >> 3);
    const int ssl   = lane & 7;

    f32x16 acc[2][2] = {};

#define QKV_STAGE(bb, kc)                                                          \
    {                                                                              \
        _Pragma("unroll")                                                          \
        for (int u = 0; u < 4; ++u) {                                              \
            int ch  = w * 4 + u;                                                   \
            int row = ch * 8 + srow0;                                              \
            gl_lds16(&zh[(size_t)(m0 + row) * E_ + (kc) * 64 + ((ssl ^ (row & 7)) << 3)], \
                     &Ah[bb][ch * 512]);                                           \
            gl_lds16(&Tall[(size_t)(n0 + row) * E_ + (kc) * 64 + ((ssl ^ (row & 7)) << 3)], \
                     &Bs[bb][ch * 512]);                                           \
        }                                                                          \
    }

    QKV_STAGE(0, 0);
    __syncthreads();                 // buf0 staged & drained
    int cur = 0;

    for (int kc = 0; kc < 16; ++kc) {
        if (kc < 15) QKV_STAGE(cur ^ 1, kc + 1);   // issue next tile first
        __builtin_amdgcn_s_setprio(1);
        #pragma unroll
        for (int ks = 0; ks < 4; ++ks) {
            half8v fb[2];
            #pragma unroll
            for (int nb = 0; nb < 2; ++nb) {
                int br = wn * 64 + nb * 32 + l31;
                fb[nb] = *(const half8v*)&Bs[cur][br * 64 + (((ks * 2 + hq) ^ (br & 7)) << 3)];
            }
            #pragma unroll
            for (int mb = 0; mb < 2; ++mb) {
                int ar = wm * 64 + mb * 32 + l31;
                half8v fa = *(const half8v*)&Ah[cur][ar * 64 + (((ks * 2 + hq) ^ (ar & 7)) << 3)];
                acc[mb][0] = MFMAH(fa, fb[0], acc[mb][0]);
                acc[mb][1] = MFMAH(fa, fb[1], acc[mb][1]);
            }
        }
        __builtin_amdgcn_s_setprio(0);
        WAITV(0);                    // next tile landed (covered by MFMA phase)
        SBAR();                      // all waves done reading buf[cur]
        cur ^= 1;
    }

    // epilogue: bias (+ Q scale) + bf16 scatter to (BH,L,DH)
    #pragma unroll
    for (int nb = 0; nb < 2; ++nb) {
        int n  = n0 + wn * 64 + nb * 32 + l31;   // fused n
        int nn = n & 1023;
        int h  = nn >> 6, dh = nn & 63;
        float bb = bias[nn];
        #pragma unroll
        for (int mb = 0; mb < 2; ++mb) {
            #pragma unroll
            for (int r = 0; r < 16; ++r) {
                int m  = m0 + wm * 64 + mb * 32 + (r & 3) + 8 * (r >> 2) + 4 * hq;
                int b  = m >> 11, i = m & (L_ - 1);
                out[((size_t)(b * H_ + h) * L_ + i) * DH_ + dh] = f2bf((acc[mb][nb][r] + bb) * osc);
            }
        }
    }
#undef QKV_STAGE
}

// ---------------------------------------------------------------------------
// Kernel 2 (FUSED): column sums D_j = sum_i x_i*exp2(S'_ij), then directly
// emits Vt[bh][dh][j] = bf16(x_j * V / D_j) via LDS-arena transpose.
// 8 waves: 2 j-groups (64 j, kf[2][4]) x 4 i-quarters (64-row chunks).
// Grid (bh=32, jchunk=16) = 512 blocks -> 2 blocks/CU (was 1: grid-limited).
// ---------------------------------------------------------------------------
__global__ __launch_bounds__(512) void col_stats_vt(
    const unsigned short* __restrict__ Qb, const unsigned short* __restrict__ Kb,
    const unsigned short* __restrict__ Vb, const float* __restrict__ x,
    unsigned short* __restrict__ Vt)
{
    __shared__ unsigned short Qlds[4][2][64 * 64];    // 64KB; reused as vt arena
    __shared__ float xlds[L_];                        // 8KB
    __shared__ float cD[3][2][64];                    // partials from ih=1,2,3
    __shared__ float sc[128];

    const int t    = threadIdx.x;
    const int lane = t & 63;
    const int wv   = t >> 6;
    const int jwv  = wv & 1;          // j-group (64 j)
    const int ih   = wv >> 1;         // i-quarter (512 i)
    const int l31  = lane & 31;
    const int hq   = lane >> 5;
    const int bh   = blockIdx.x;
    const int b    = bh >> 4;
    const int jc0  = blockIdx.y * 128;
    const int j0   = jc0 + jwv * 64;

    const int srow0 = (lane >> 3);
    const int ssl   = lane & 7;

    *(float4*)&xlds[t * 4] = *(const float4*)&x[(size_t)b * L_ + t * 4];

    short8v kf[2][4];
    #pragma unroll
    for (int s = 0; s < 2; ++s) {
        const unsigned short* kp = Kb + ((size_t)bh * L_ + j0 + s * 32 + l31) * DH_ + hq * 8;
        #pragma unroll
        for (int c = 0; c < 4; ++c) kf[s][c] = *(const short8v*)(kp + c * 16);
    }

    float d0[16], d1[16];
    #pragma unroll
    for (int r = 0; r < 16; ++r) { d0[r] = 0.f; d1[r] = 0.f; }

    // i-chunks: quarter ih covers chunks (ih*8 + lt)*64 rows, lt in [0,8)
#define CS_STAGE(bb, lt)                                                            \
    {                                                                               \
        _Pragma("unroll")                                                           \
        for (int u = 0; u < 4; ++u) {                                               \
            int ch  = jwv * 4 + u;                                                  \
            int row = ch * 8 + srow0;                                               \
            gl_lds16(&Qb[((size_t)bh * L_ + (size_t)(ih * 8 + (lt)) * 64 + row) * DH_ + ((ssl ^ (row & 7)) << 3)], \
                     &Qlds[ih][bb][ch * 512]);                                      \
        }                                                                           \
    }

    CS_STAGE(0, 0);
    CS_STAGE(1, 1);
    __syncthreads();                 // drains loads AND xlds ds_writes
    int cur = 0;

    for (int lt = 0; lt < 8; ++lt) {
        if (lt < 7) WAITV(4); else WAITV(0);
        SBAR();
        #pragma unroll
        for (int cc = 0; cc < 2; ++cc) {
            f32x16 a0 = {}, a1 = {};
            __builtin_amdgcn_s_setprio(1);
            #pragma unroll
            for (int c = 0; c < 4; ++c) {
                int qr = cc * 32 + l31;
                short8v qv = *(const short8v*)&Qlds[ih][cur][qr * 64 + (((c * 2 + hq) ^ (qr & 7)) << 3)];
                a0 = MFMA32(kf[0][c], qv, a0);
                a1 = MFMA32(kf[1][c], qv, a1);
            }
            __builtin_amdgcn_s_setprio(0);
            float xi = xlds[(ih * 8 + lt) * 64 + cc * 32 + l31];
            #pragma unroll
            for (int r = 0; r < 16; ++r) {
                d0[r] += xi * __builtin_amdgcn_exp2f(a0[r]);
                d1[r] += xi * __builtin_amdgcn_exp2f(a1[r]);
            }
        }
        SBAR();
        if (lt + 2 < 8) CS_STAGE(cur, lt + 2);
        cur ^= 1;
    }

    #pragma unroll
    for (int r = 0; r < 16; ++r) {
        #pragma unroll
        for (int off = 16; off > 0; off >>= 1) {
            d0[r] += __shfl_xor(d0[r], off);
            d1[r] += __shfl_xor(d1[r], off);
        }
    }
    // combine the four i-quarters via LDS
    if (ih > 0 && l31 == 0) {
        #pragma unroll
        for (int r = 0; r < 16; ++r) {
            int jr = 4 * hq + (r & 3) + 8 * (r >> 2);
            cD[ih - 1][jwv][jr]      = d0[r];
            cD[ih - 1][jwv][32 + jr] = d1[r];
        }
    }
    __syncthreads();
    if (ih == 0 && l31 == 0) {
        #pragma unroll
        for (int r = 0; r < 16; ++r) {
            int jr = 4 * hq + (r & 3) + 8 * (r >> 2);
            float D0 = d0[r] + cD[0][jwv][jr]      + cD[1][jwv][jr]      + cD[2][jwv][jr];
            float D1 = d1[r] + cD[0][jwv][32 + jr] + cD[1][jwv][32 + jr] + cD[2][jwv][32 + jr];
            sc[jwv * 64 + jr]      = xlds[j0 + jr]      / D0;
            sc[jwv * 64 + 32 + jr] = xlds[j0 + 32 + jr] / D1;
        }
    }
    __syncthreads();                 // sc ready; Qlds arena free

    // ---- fused Vt emit: 2 tiles of 64j x 64dh, both at once via Qlds arena --
    {
        unsigned short (*vtb)[66] = (unsigned short(*)[66])&Qlds[0][0][0];
        const int half = t >> 8;          // tile 0/1
        const int tl   = t & 255;
        int jb = jc0 + half * 64;
        unsigned short (*vbuf)[66] = vtb + half * 64;
        #pragma unroll
        for (int u = 0; u < 2; ++u) {
            int idx = tl + 256 * u;
            int row = idx >> 3, off = (idx & 7) * 8;
            short8v v = *(const short8v*)&Vb[((size_t)bh * L_ + jb + row) * DH_ + off];
            float s = sc[half * 64 + row];
            const unsigned short* vs = (const unsigned short*)&v;
            #pragma unroll
            for (int k = 0; k < 8; ++k)
                vbuf[row][off + k] = f2bf(bf2f(vs[k]) * s);
        }
        __syncthreads();
        #pragma unroll
        for (int u = 0; u < 2; ++u) {
            int idx = tl + 256 * u;
            int dh = idx >> 3, js = (idx & 7) * 8;
            unsigned short o[8];
            #pragma unroll
            for (int k = 0; k < 8; ++k) o[k] = vbuf[js + k][dh];
            *(short8v*)&Vt[((size_t)bh * DH_ + dh) * L_ + jb + js] = *(const short8v*)o;
        }
    }
#undef CS_STAGE
}

// ---------------------------------------------------------------------------
// Kernel 3: attention output. P = exp2(S'), O = x_i * (P @ Vt^T).
// 8 waves: 4 i-groups x 2 j-halves; counted-vmcnt 2-deep; T12 in-register P.
// 64KB K/V arena reused as combine buffer => 2 blocks/CU. (R20-proven)
// ---------------------------------------------------------------------------
__global__ __launch_bounds__(512) void attn_out_mfma(
    const unsigned short* __restrict__ Qb, const unsigned short* __restrict__ Kb,
    const unsigned short* __restrict__ Vt, const float* __restrict__ x,
    _Float16* __restrict__ Of)
{
    __shared__ unsigned short KVa[8][64 * 64];   // K: [jh*2+bb], V: [4+jh*2+bb]

    const int t    = threadIdx.x;
    const int lane = t & 63;
    const int wv   = t >> 6;
    const int iwv  = wv & 3;          // i-group (64 rows)
    const int jh   = wv >> 2;         // j-half (0 or 1)
    const int l31  = lane & 31;
    const int hq   = lane >> 5;
    const int bh   = blockIdx.x;
    const int b    = bh >> 4, hh = bh & 15;
    const int iw   = blockIdx.y * 256 + iwv * 64;

    const int srow0 = (lane >> 3);
    const int ssl   = lane & 7;

    short8v qf[2][4];
    #pragma unroll
    for (int ig = 0; ig < 2; ++ig) {
        const unsigned short* qp = Qb + ((size_t)bh * L_ + iw + ig * 32 + l31) * DH_ + hq * 8;
        #pragma unroll
        for (int c = 0; c < 4; ++c) qf[ig][c] = *(const short8v*)(qp + c * 16);
    }

    f32x16 accO[2][2] = {};   // [igroup][dh-half]

#define AO_STAGE(bb, jt)                                                            \
    {                                                                               \
        _Pragma("unroll")                                                           \
        for (int u = 0; u < 2; ++u) {                                               \
            int ch  = iwv * 2 + u;                                                  \
            int row = ch * 8 + srow0;                                               \
            gl_lds16(&Kb[((size_t)bh * L_ + (jt) * 64 + row) * DH_ + ((ssl ^ (row & 7)) << 3)], \
                     &KVa[jh * 2 + (bb)][ch * 512]);                                \
            gl_lds16(&Vt[((size_t)bh * DH_ + row) * L_ + (jt) * 64 + ((ssl ^ (row & 7)) << 3)], \
                     &KVa[4 + jh * 2 + (bb)][ch * 512]);                            \
        }                                                                           \
    }

    AO_STAGE(0, jh * 16 + 0);
    AO_STAGE(1, jh * 16 + 1);
    __syncthreads();
    int cur = 0;

    for (int ltj = 0; ltj < 16; ++ltj) {
        if (ltj < 15) WAITV(4); else WAITV(0);
        SBAR();

        // ---- QK^T (two i-groups share each K-fragment) + T12 P packing ----
        uint4 pa[2][4];
        #pragma unroll
        for (int js = 0; js < 2; ++js) {
            f32x16 as0 = {}, as1 = {};
            __builtin_amdgcn_s_setprio(1);
            #pragma unroll
            for (int c = 0; c < 4; ++c) {
                int krow = js * 32 + l31;
                short8v kfr = *(const short8v*)&KVa[jh * 2 + cur][krow * 64 + (((c * 2 + hq) ^ (krow & 7)) << 3)];
                as0 = MFMA32(kfr, qf[0][c], as0);
                as1 = MFMA32(kfr, qf[1][c], as1);
            }
            __builtin_amdgcn_s_setprio(0);
            #pragma unroll
            for (int ig = 0; ig < 2; ++ig) {
                const f32x16& as = (ig == 0) ? as0 : as1;
                float p[16];
                #pragma unroll
                for (int r = 0; r < 16; ++r) p[r] = __builtin_amdgcn_exp2f(as[r]);

                unsigned P0 = pack2_bf16(p[0], p[1]);
                unsigned P1 = pack2_bf16(p[2], p[3]);
                unsigned Q0 = pack2_bf16(p[4], p[5]);
                unsigned Q1 = pack2_bf16(p[6], p[7]);
                asm("v_permlane32_swap_b32 %0, %1" : "+v"(P0), "+v"(Q0));
                asm("v_permlane32_swap_b32 %0, %1" : "+v"(P1), "+v"(Q1));
                pa[ig][js * 2 + 0] = make_uint4(P0, P1, Q0, Q1);

                unsigned R0 = pack2_bf16(p[8],  p[9]);
                unsigned R1 = pack2_bf16(p[10], p[11]);
                unsigned S0 = pack2_bf16(p[12], p[13]);
                unsigned S1 = pack2_bf16(p[14], p[15]);
                asm("v_permlane32_swap_b32 %0, %1" : "+v"(R0), "+v"(S0));
                asm("v_permlane32_swap_b32 %0, %1" : "+v"(R1), "+v"(S1));
                pa[ig][js * 2 + 1] = make_uint4(R0, R1, S0, S1);
            }
        }

        // ---- O += P · Vt^T (two i-groups share each V-fragment) ----
        __builtin_amdgcn_s_setprio(1);
        #pragma unroll
        for (int c = 0; c < 4; ++c) {
            union { uint4 u; short8v s; } pa0, pa1;
            pa0.u = pa[0][c]; pa1.u = pa[1][c];
            int r0 = l31, r1 = 32 + l31;
            short8v vf0 = *(const short8v*)&KVa[4 + jh * 2 + cur][r0 * 64 + (((c * 2 + hq) ^ (r0 & 7)) << 3)];
            short8v vf1 = *(const short8v*)&KVa[4 + jh * 2 + cur][r1 * 64 + (((c * 2 + hq) ^ (r1 & 7)) << 3)];
            accO[0][0] = MFMA32(pa0.s, vf0, accO[0][0]);
            accO[0][1] = MFMA32(pa0.s, vf1, accO[0][1]);
            accO[1][0] = MFMA32(pa1.s, vf0, accO[1][0]);
            accO[1][1] = MFMA32(pa1.s, vf1, accO[1][1]);
        }
        __builtin_amdgcn_s_setprio(0);
        SBAR();
        if (ltj + 2 < 16) AO_STAGE(cur, jh * 16 + ltj + 2);
        cur ^= 1;
    }

    // ---- combine j-halves: REUSE the K/V arena (all reads done at last SBAR).
    float* comb = (float*)&KVa[0][0];            // 4 * 64 * 64 floats = 64KB
    if (jh == 1) {
        float* cb = comb + iwv * 4096 + lane;
        #pragma unroll
        for (int g = 0; g < 2; ++g)
            #pragma unroll
            for (int h = 0; h < 2; ++h)
                #pragma unroll
                for (int r = 0; r < 16; ++r)
                    cb[((g * 2 + h) * 16 + r) * 64] = accO[g][h][r];
    }
    __syncthreads();
    if (jh == 0) {
        const float* cb = comb + iwv * 4096 + lane;
        #pragma unroll
        for (int g = 0; g < 2; ++g)
            #pragma unroll
            for (int h = 0; h < 2; ++h)
                #pragma unroll
                for (int r = 0; r < 16; ++r)
                    accO[g][h][r] += cb[((g * 2 + h) * 16 + r) * 64];

        #pragma unroll
        for (int ig = 0; ig < 2; ++ig) {
            #pragma unroll
            for (int q = 0; q < 4; ++q) {
                float4 xq = *(const float4*)&x[(size_t)b * L_ + iw + ig * 32 + 4 * hq + 8 * q];
                const float xs[4] = { xq.x, xq.y, xq.z, xq.w };
                #pragma unroll
                for (int k = 0; k < 4; ++k) {
                    int r    = q * 4 + k;
                    int irow = iw + ig * 32 + 4 * hq + 8 * q + k;
                    size_t base = ((size_t)b * L_ + irow) * E_ + hh * DH_;
                    Of[base + l31]      = (_Float16)(accO[ig][0][r] * xs[k]);
                    Of[base + 32 + l31] = (_Float16)(accO[ig][1][r] * xs[k]);
                }
            }
        }
    }
#undef AO_STAGE
}

// ---------------------------------------------------------------------------
// Kernel 4: fused MLP, fp16 MFMA, 128x128, BK=64.
// Min-2-phase pipeline: one barrier per K-step. (R19-proven)
// Grid (m=32, n=32); y pre-zeroed; b2 folded at n-block 0.
// ---------------------------------------------------------------------------
__global__ __launch_bounds__(256) void mlp_mfma(
    const _Float16* __restrict__ Of, const _Float16* __restrict__ W1t,
    const float* __restrict__ b1, const float* __restrict__ W2,
    const float* __restrict__ b2, float* __restrict__ y)
{
    __shared__ _Float16 Oh[2][128 * 64];
    __shared__ _Float16 Wh[2][128 * 64];

    const int t    = threadIdx.x;
    const int lane = t & 63;
    const int w    = t >> 6;
    const int l31  = lane & 31;
    const int hq   = lane >> 5;
    const int wm   = w >> 1, wn = w & 1;
    const int m0   = blockIdx.x * 128;
    const int n0   = blockIdx.y * 128;

    const int srow0 = (lane >> 3);
    const int ssl   = lane & 7;

    f32x16 acc[2][2] = {};

#define MLP_STAGE(bb, kc)                                                          \
    {                                                                              \
        _Pragma("unroll")                                                          \
        for (int u = 0; u < 4; ++u) {                                              \
            int ch  = w * 4 + u;                                                   \
            int row = ch * 8 + srow0;                                              \
            gl_lds16(&Of[(size_t)(m0 + row) * E_ + (kc) * 64 + ((ssl ^ (row & 7)) << 3)], \
                     &Oh[bb][ch * 512]);                                           \
            gl_lds16(&W1t[(size_t)(n0 + row) * E_ + (kc) * 64 + ((ssl ^ (row & 7)) << 3)], \
                     &Wh[bb][ch * 512]);                                           \
        }                                                                          \
    }

    MLP_STAGE(0, 0);
    __syncthreads();                 // buf0 staged & drained
    int cur = 0;

    for (int kc = 0; kc < 16; ++kc) {
        if (kc < 15) MLP_STAGE(cur ^ 1, kc + 1);   // issue next tile first
        __builtin_amdgcn_s_setprio(1);
        #pragma unroll
        for (int ks = 0; ks < 4; ++ks) {
            half8v fb[2];
            #pragma unroll
            for (int nb = 0; nb < 2; ++nb) {
                int br = wn * 64 + nb * 32 + l31;
                fb[nb] = *(const half8v*)&Wh[cur][br * 64 + (((ks * 2 + hq) ^ (br & 7)) << 3)];
            }
            #pragma unroll
            for (int mb = 0; mb < 2; ++mb) {
                int ar = wm * 64 + mb * 32 + l31;
                half8v fa = *(const half8v*)&Oh[cur][ar * 64 + (((ks * 2 + hq) ^ (ar & 7)) << 3)];
                acc[mb][0] = MFMAH(fa, fb[0], acc[mb][0]);
                acc[mb][1] = MFMAH(fa, fb[1], acc[mb][1]);
            }
        }
        __builtin_amdgcn_s_setprio(0);
        WAITV(0);                    // next tile landed (covered by MFMA phase)
        SBAR();                      // all waves done reading buf[cur]
        cur ^= 1;
    }

    // epilogue: gelu + W2 dot; reduce over 32 lanes; atomicAdd per row.
    const int hid0 = n0 + wn * 64 + l31;
    const float bb0 = b1[hid0],      w20 = W2[hid0];
    const float bb1 = b1[hid0 + 32], w21 = W2[hid0 + 32];
    const float b2v = (blockIdx.y == 0) ? b2[0] : 0.0f;
    #pragma unroll
    for (int mb = 0; mb < 2; ++mb) {
        #pragma unroll
        for (int r = 0; r < 16; ++r) {
            float h0 = acc[mb][0][r] + bb0;
            float h1 = acc[mb][1][r] + bb1;
            float s  = 0.5f * h0 * (1.0f + erf_fast(h0 * 0.70710678f)) * w20
                     + 0.5f * h1 * (1.0f + erf_fast(h1 * 0.70710678f)) * w21;
            #pragma unroll
            for (int off = 16; off > 0; off >>= 1) s += __shfl_xor(s, off);
            if (l31 == 0) {
                int m = m0 + wm * 64 + mb * 32 + (r & 3) + 8 * (r >> 2) + 4 * hq;
                atomicAdd(&y[m], s + b2v);
            }
        }
    }
#undef MLP_STAGE
}

// ---------------------------------------------------------------------------
extern "C" void kernel_launch(void* const* d_in, const int* in_sizes, int n_in,
                              void* d_out, int out_size, void* d_ws, size_t ws_size,
                              hipStream_t stream)
{
    const float* x  = (const float*)d_in[0];
    const float* z  = (const float*)d_in[1];
    const float* Wq = (const float*)d_in[2];
    const float* bq = (const float*)d_in[3];
    const float* Wk = (const float*)d_in[4];
    const float* bk = (const float*)d_in[5];
    const float* Wv = (const float*)d_in[6];
    const float* bv = (const float*)d_in[7];
    const float* W1 = (const float*)d_in[8];
    const float* b1 = (const float*)d_in[9];
    const float* W2 = (const float*)d_in[10];
    const float* b2 = (const float*)d_in[11];
    float* y = (float*)d_out;

    const size_t NQ = (size_t)BH_ * L_ * DH_;        // 4.19M elems
    unsigned short* p = (unsigned short*)d_ws;
    unsigned short* Qb  = p;  p += NQ;               // Qb|Kb|Vb contiguous
    unsigned short* Kb  = p;  p += NQ;
    unsigned short* Vb  = p;  p += NQ;
    unsigned short* Vt  = p;  p += NQ;
    _Float16* zh  = (_Float16*)p;  p += (size_t)NROW_ * E_;
    _Float16* Tq  = (_Float16*)p;  p += (size_t)E_ * E_;   // Tq|Tk|Tv contiguous
    _Float16* Tk  = (_Float16*)p;  p += (size_t)E_ * E_;
    _Float16* Tv  = (_Float16*)p;  p += (size_t)E_ * E_;
    _Float16* W1t = (_Float16*)p;  p += (size_t)HID_ * E_;
    _Float16* Ofp = (_Float16*)p;  p += (size_t)NROW_ * E_;

    hipMemsetAsync(y, 0, (size_t)out_size * sizeof(float), stream);

    prep_all<<<dim3(3840), 256, 0, stream>>>(
        z, zh, Wq, Wk, Wv, Tq, Tk, Tv, W1, W1t);

    qkv_mfma<<<dim3(3 * E_ / 128, NROW_ / 128), 256, 0, stream>>>(
        zh, Tq, bq, bk, bv, Qb);

    col_stats_vt<<<dim3(BH_, L_ / 128), 512, 0, stream>>>(Qb, Kb, Vb, x, Vt);

    attn_out_mfma<<<dim3(BH_, L_ / 256), 512, 0, stream>>>(Qb, Kb, Vt, x, Ofp);

    mlp_mfma<<<dim3(NROW_ / 128, HID_ / 128), 256, 0, stream>>>(
        Ofp, W1t, b1, W2, b2, y);
}

// Round 23
// 187.579 us; speedup vs baseline: 1.0496x; 1.0496x over previous
//
#include <hip/hip_runtime.h>
#include <hip/hip_bf16.h>
#include <math.h>

#define B_    2
#define L_    2048
#define E_    1024
#define H_    16
#define DH_   64
#define HID_  4096
#define NROW_ (B_*L_)   // 4096
#define BH_   (B_*H_)   // 32

// 0.125 (1/sqrt(DH)) * log2(e): Q pre-scale so P = exp2(S')
#define QSCL  0.18033688011112042f

typedef __attribute__((ext_vector_type(8)))  short    short8v;
typedef _Float16 half8v __attribute__((ext_vector_type(8)));
typedef __attribute__((ext_vector_type(16))) float    f32x16;

#define MFMA32(A, Bv, C) __builtin_amdgcn_mfma_f32_32x32x16_bf16((A), (Bv), (C), 0, 0, 0)
#define MFMAH(A, Bv, C)  __builtin_amdgcn_mfma_f32_32x32x16_f16((A), (Bv), (C), 0, 0, 0)

#define WAITV(N) asm volatile("s_waitcnt vmcnt(" #N ")" ::: "memory")
#define SBAR()   __builtin_amdgcn_s_barrier()

// float->bf16 round-half-up (2 ops).
__device__ __forceinline__ unsigned short f2bf(float f) {
    union { float f; unsigned u; } v; v.f = f;
    return (unsigned short)((v.u + 0x8000u) >> 16);
}
// pack two floats -> {bf16(hi), bf16(lo)} in 3 VALU ops via v_perm_b32
__device__ __forceinline__ unsigned pack2_bf16(float lo, float hi) {
    union { float f; unsigned u; } a, b; a.f = lo; b.f = hi;
    return __builtin_amdgcn_perm(b.u + 0x8000u, a.u + 0x8000u, 0x07060302u);
}
__device__ __forceinline__ float bf2f(unsigned short u) {
    union { unsigned u; float f; } v; v.u = ((unsigned)u) << 16;
    return v.f;
}

// async global->LDS, 16B per lane. Dest is wave-uniform base + lane*16.
__device__ __forceinline__ void gl_lds16(const void* g, void* l) {
    __builtin_amdgcn_global_load_lds(
        (const __attribute__((address_space(1))) unsigned int*)g,
        (__attribute__((address_space(3))) unsigned int*)l, 16, 0, 0);
}

// Abramowitz-Stegun 7.1.26, |abs err| < 1.5e-7
__device__ __forceinline__ float erf_fast(float v) {
    float a = fabsf(v);
    float t = __builtin_amdgcn_rcpf(1.0f + 0.3275911f * a);
    float p = t * (0.254829592f + t * (-0.284496736f + t * (1.421413741f +
              t * (-1.453152027f + t * 1.061405429f))));
    float r = 1.0f - p * __expf(-a * a);
    return copysignf(r, v);
}

// ---------------------------------------------------------------------------
// Kernel 0 (FUSED PREPS): one dispatch covering
//   blocks [0,2048):     zh = fp16(z)                     (no LDS)
//   blocks [2048,2816):  Tq/Tk/Tv = transpose+cast W*     (LDS tile)
//   blocks [2816,3840):  W1t = transpose+cast W1          (LDS tile)
// ---------------------------------------------------------------------------
__global__ __launch_bounds__(256) void prep_all(
    const float* __restrict__ z, _Float16* __restrict__ zh,
    const float* __restrict__ Wq, const float* __restrict__ Wk,
    const float* __restrict__ Wv,
    _Float16* __restrict__ Tq, _Float16* __restrict__ Tk,
    _Float16* __restrict__ Tv,
    const float* __restrict__ W1, _Float16* __restrict__ W1t)
{
    __shared__ float tile[64][65];
    const int blk = blockIdx.x;
    const int t   = threadIdx.x;

    if (blk < 2048) {
        const size_t i = ((size_t)blk * 256 + t) * 8;
        float4 a = *(const float4*)&z[i];
        float4 b = *(const float4*)&z[i + 4];
        union { _Float16 h[8]; half8v v; } o;
        o.h[0] = (_Float16)a.x; o.h[1] = (_Float16)a.y;
        o.h[2] = (_Float16)a.z; o.h[3] = (_Float16)a.w;
        o.h[4] = (_Float16)b.x; o.h[5] = (_Float16)b.y;
        o.h[6] = (_Float16)b.z; o.h[7] = (_Float16)b.w;
        *(half8v*)&zh[i] = o.v;
        return;
    }

    const float* src;
    _Float16*    dst;
    int r0, c0, ldd;
    if (blk < 2816) {
        int idx   = blk - 2048;
        int which = idx >> 8;
        int rem   = idx & 255;
        int bx    = rem & 15, by = rem >> 4;
        src = (which == 0) ? Wq : (which == 1) ? Wk : Wv;
        dst = (which == 0) ? Tq : (which == 1) ? Tk : Tv;
        r0 = by * 64; c0 = bx * 64; ldd = E_;
        #pragma unroll
        for (int u = 0; u < 4; ++u) {
            int f = t + 256 * u, row = f >> 4, c4 = (f & 15) << 2;
            *(float4*)&tile[row][c4] = *(const float4*)&src[(size_t)(r0 + row) * E_ + c0 + c4];
        }
    } else {
        int idx = blk - 2816;
        int bx  = idx & 63, by = idx >> 6;
        src = W1; dst = W1t;
        r0 = by * 64; c0 = bx * 64; ldd = E_;
        #pragma unroll
        for (int u = 0; u < 4; ++u) {
            int f = t + 256 * u, row = f >> 4, c4 = (f & 15) << 2;
            *(float4*)&tile[row][c4] = *(const float4*)&src[(size_t)(r0 + row) * HID_ + c0 + c4];
        }
    }
    __syncthreads();
    #pragma unroll
    for (int u = 0; u < 4; ++u) {
        int f = t + 256 * u, c = f >> 4, r4 = (f & 15) << 2;
        union { _Float16 h[4]; uint2 u2; } pk;
        pk.h[0] = (_Float16)tile[r4 + 0][c];
        pk.h[1] = (_Float16)tile[r4 + 1][c];
        pk.h[2] = (_Float16)tile[r4 + 2][c];
        pk.h[3] = (_Float16)tile[r4 + 3][c];
        *(uint2*)&dst[(size_t)(c0 + c) * ldd + r0 + r4] = pk.u2;
    }
}

// ---------------------------------------------------------------------------
// Kernel 1: fused QKV projection, fp16 MFMA, 128x128 tile, BK=64, 4 waves.
// Min-2-phase pipeline: one barrier per K-step. (R19-proven)
// ---------------------------------------------------------------------------
__global__ __launch_bounds__(256) void qkv_mfma(
    const _Float16* __restrict__ zh,
    const _Float16* __restrict__ Tall,      // fused [3072][1024]
    const float* __restrict__ bq, const float* __restrict__ bk,
    const float* __restrict__ bv,
    unsigned short* __restrict__ outQKV)    // Qb | Kb | Vb contiguous
{
    const int which = blockIdx.x >> 3;      // 1024/128 = 8 tiles per weight
    const float* bias = (which == 0) ? bq : (which == 1) ? bk : bv;
    const float  osc  = (which == 0) ? QSCL : 1.0f;
    unsigned short* out = outQKV + (size_t)which * ((size_t)BH_ * L_ * DH_);

    __shared__ _Float16 Ah[2][128 * 64];
    __shared__ _Float16 Bs[2][128 * 64];

    const int t    = threadIdx.x;
    const int lane = t & 63;
    const int w    = t >> 6;
    const int l31  = lane & 31;
    const int hq   = lane >> 5;
    const int wm   = w >> 1, wn = w & 1;
    const int m0   = blockIdx.y * 128;
    const int n0   = blockIdx.x * 128;      // global fused n

    const int srow0 = (lane >> 3);
    const int ssl   = lane & 7;

    f32x16 acc[2][2] = {};

#define QKV_STAGE(bb, kc)                                                          \
    {                                                                              \
        _Pragma("unroll")                                                          \
        for (int u = 0; u < 4; ++u) {                                              \
            int ch  = w * 4 + u;                                                   \
            int row = ch * 8 + srow0;                                              \
            gl_lds16(&zh[(size_t)(m0 + row) * E_ + (kc) * 64 + ((ssl ^ (row & 7)) << 3)], \
                     &Ah[bb][ch * 512]);                                           \
            gl_lds16(&Tall[(size_t)(n0 + row) * E_ + (kc) * 64 + ((ssl ^ (row & 7)) << 3)], \
                     &Bs[bb][ch * 512]);                                           \
        }                                                                          \
    }

    QKV_STAGE(0, 0);
    __syncthreads();                 // buf0 staged & drained
    int cur = 0;

    for (int kc = 0; kc < 16; ++kc) {
        if (kc < 15) QKV_STAGE(cur ^ 1, kc + 1);   // issue next tile first
        __builtin_amdgcn_s_setprio(1);
        #pragma unroll
        for (int ks = 0; ks < 4; ++ks) {
            half8v fb[2];
            #pragma unroll
            for (int nb = 0; nb < 2; ++nb) {
                int br = wn * 64 + nb * 32 + l31;
                fb[nb] = *(const half8v*)&Bs[cur][br * 64 + (((ks * 2 + hq) ^ (br & 7)) << 3)];
            }
            #pragma unroll
            for (int mb = 0; mb < 2; ++mb) {
                int ar = wm * 64 + mb * 32 + l31;
                half8v fa = *(const half8v*)&Ah[cur][ar * 64 + (((ks * 2 + hq) ^ (ar & 7)) << 3)];
                acc[mb][0] = MFMAH(fa, fb[0], acc[mb][0]);
                acc[mb][1] = MFMAH(fa, fb[1], acc[mb][1]);
            }
        }
        __builtin_amdgcn_s_setprio(0);
        WAITV(0);                    // next tile landed (covered by MFMA phase)
        SBAR();                      // all waves done reading buf[cur]
        cur ^= 1;
    }

    // epilogue: bias (+ Q scale) + bf16 scatter to (BH,L,DH)
    #pragma unroll
    for (int nb = 0; nb < 2; ++nb) {
        int n  = n0 + wn * 64 + nb * 32 + l31;   // fused n
        int nn = n & 1023;
        int h  = nn >> 6, dh = nn & 63;
        float bb = bias[nn];
        #pragma unroll
        for (int mb = 0; mb < 2; ++mb) {
            #pragma unroll
            for (int r = 0; r < 16; ++r) {
                int m  = m0 + wm * 64 + mb * 32 + (r & 3) + 8 * (r >> 2) + 4 * hq;
                int b  = m >> 11, i = m & (L_ - 1);
                out[((size_t)(b * H_ + h) * L_ + i) * DH_ + dh] = f2bf((acc[mb][nb][r] + bb) * osc);
            }
        }
    }
#undef QKV_STAGE
}

// ---------------------------------------------------------------------------
// Kernel 2 (FUSED): column sums D_j = sum_i x_i*exp2(S'_ij), then directly
// emits Vt[bh][dh][j] = bf16(x_j * V / D_j) via LDS-arena transpose.
// 8 waves: 4 j-groups x 2 i-halves; grid (bh=32, jchunk=8). (R17/R21-proven)
// ---------------------------------------------------------------------------
__global__ __launch_bounds__(512) void col_stats_vt(
    const unsigned short* __restrict__ Qb, const unsigned short* __restrict__ Kb,
    const unsigned short* __restrict__ Vb, const float* __restrict__ x,
    unsigned short* __restrict__ Vt)
{
    __shared__ unsigned short Qlds[2][2][128 * 64];   // 64KB; reused as vt arena
    __shared__ float xlds[L_];
    __shared__ float cD[4][64];
    __shared__ float sc[256];

    const int t    = threadIdx.x;
    const int lane = t & 63;
    const int wv   = t >> 6;
    const int jwv  = wv & 3;          // j-group
    const int ih   = wv >> 2;         // i-half
    const int l31  = lane & 31;
    const int hq   = lane >> 5;
    const int bh   = blockIdx.x;
    const int b    = bh >> 4;
    const int jc0  = blockIdx.y * 256;
    const int j0   = jc0 + jwv * 64;

    const int srow0 = (lane >> 3);
    const int ssl   = lane & 7;

    *(float4*)&xlds[t * 4] = *(const float4*)&x[(size_t)b * L_ + t * 4];

    short8v kf[2][4];
    #pragma unroll
    for (int s = 0; s < 2; ++s) {
        const unsigned short* kp = Kb + ((size_t)bh * L_ + j0 + s * 32 + l31) * DH_ + hq * 8;
        #pragma unroll
        for (int c = 0; c < 4; ++c) kf[s][c] = *(const short8v*)(kp + c * 16);
    }

    float d0[16], d1[16];
    #pragma unroll
    for (int r = 0; r < 16; ++r) { d0[r] = 0.f; d1[r] = 0.f; }

#define CS_STAGE(bb, lt)                                                            \
    {                                                                               \
        _Pragma("unroll")                                                           \
        for (int u = 0; u < 4; ++u) {                                               \
            int ch  = jwv * 4 + u;                                                  \
            int row = ch * 8 + srow0;                                               \
            gl_lds16(&Qb[((size_t)bh * L_ + (size_t)(ih * 8 + (lt)) * 128 + row) * DH_ + ((ssl ^ (row & 7)) << 3)], \
                     &Qlds[ih][bb][ch * 512]);                                      \
        }                                                                           \
    }

    CS_STAGE(0, 0);
    CS_STAGE(1, 1);
    __syncthreads();
    int cur = 0;

    for (int lt = 0; lt < 8; ++lt) {
        if (lt < 7) WAITV(4); else WAITV(0);
        SBAR();
        #pragma unroll
        for (int cc = 0; cc < 4; ++cc) {
            f32x16 a0 = {}, a1 = {};
            __builtin_amdgcn_s_setprio(1);
            #pragma unroll
            for (int c = 0; c < 4; ++c) {
                int qr = cc * 32 + l31;
                short8v qv = *(const short8v*)&Qlds[ih][cur][qr * 64 + (((c * 2 + hq) ^ (qr & 7)) << 3)];
                a0 = MFMA32(kf[0][c], qv, a0);
                a1 = MFMA32(kf[1][c], qv, a1);
            }
            __builtin_amdgcn_s_setprio(0);
            float xi = xlds[(ih * 8 + lt) * 128 + cc * 32 + l31];
            #pragma unroll
            for (int r = 0; r < 16; ++r) {
                d0[r] += xi * __builtin_amdgcn_exp2f(a0[r]);
                d1[r] += xi * __builtin_amdgcn_exp2f(a1[r]);
            }
        }
        SBAR();
        if (lt + 2 < 8) CS_STAGE(cur, lt + 2);
        cur ^= 1;
    }

    #pragma unroll
    for (int r = 0; r < 16; ++r) {
        #pragma unroll
        for (int off = 16; off > 0; off >>= 1) {
            d0[r] += __shfl_xor(d0[r], off);
            d1[r] += __shfl_xor(d1[r], off);
        }
    }
    if (ih == 1 && l31 == 0) {
        #pragma unroll
        for (int r = 0; r < 16; ++r) {
            int jr = 4 * hq + (r & 3) + 8 * (r >> 2);
            cD[jwv][jr]      = d0[r];
            cD[jwv][32 + jr] = d1[r];
        }
    }
    __syncthreads();
    if (ih == 0 && l31 == 0) {
        #pragma unroll
        for (int r = 0; r < 16; ++r) {
            int jr = 4 * hq + (r & 3) + 8 * (r >> 2);
            float D0 = d0[r] + cD[jwv][jr];
            float D1 = d1[r] + cD[jwv][32 + jr];
            sc[jwv * 64 + jr]      = xlds[j0 + jr]      / D0;
            sc[jwv * 64 + 32 + jr] = xlds[j0 + 32 + jr] / D1;
        }
    }

    // ---- fused Vt emit: 4 tiles of 64j x 64dh, 2 at a time via Qlds arena ----
    unsigned short (*vtb)[66] = (unsigned short(*)[66])&Qlds[0][0][0];
    const int half = t >> 8;          // 0/1: which tile of the pair
    const int tl   = t & 255;
    #pragma unroll
    for (int it = 0; it < 2; ++it) {
        int tt = it * 2 + half;           // tile 0..3
        int jb = jc0 + tt * 64;
        unsigned short (*vbuf)[66] = vtb + half * 64;
        __syncthreads();                   // sc ready (it=0) / buffer free (it=1)
        #pragma unroll
        for (int u = 0; u < 2; ++u) {
            int idx = tl + 256 * u;
            int row = idx >> 3, off = (idx & 7) * 8;
            short8v v = *(const short8v*)&Vb[((size_t)bh * L_ + jb + row) * DH_ + off];
            float s = sc[tt * 64 + row];
            const unsigned short* vs = (const unsigned short*)&v;
            #pragma unroll
            for (int k = 0; k < 8; ++k)
                vbuf[row][off + k] = f2bf(bf2f(vs[k]) * s);
        }
        __syncthreads();
        #pragma unroll
        for (int u = 0; u < 2; ++u) {
            int idx = tl + 256 * u;
            int dh = idx >> 3, js = (idx & 7) * 8;
            unsigned short o[8];
            #pragma unroll
            for (int k = 0; k < 8; ++k) o[k] = vbuf[js + k][dh];
            *(short8v*)&Vt[((size_t)bh * DH_ + dh) * L_ + jb + js] = *(const short8v*)o;
        }
    }
#undef CS_STAGE
}

// ---------------------------------------------------------------------------
// Kernel 3: attention output. P = exp2(S'), O = x_i * (P @ Vt^T).
// 8 waves: 4 i-groups x 2 j-halves; counted-vmcnt 2-deep; T12 in-register P.
// 64KB K/V arena reused as combine buffer => 2 blocks/CU. (R20-proven)
// ---------------------------------------------------------------------------
__global__ __launch_bounds__(512) void attn_out_mfma(
    const unsigned short* __restrict__ Qb, const unsigned short* __restrict__ Kb,
    const unsigned short* __restrict__ Vt, const float* __restrict__ x,
    _Float16* __restrict__ Of)
{
    __shared__ unsigned short KVa[8][64 * 64];   // K: [jh*2+bb], V: [4+jh*2+bb]

    const int t    = threadIdx.x;
    const int lane = t & 63;
    const int wv   = t >> 6;
    const int iwv  = wv & 3;          // i-group (64 rows)
    const int jh   = wv >> 2;         // j-half (0 or 1)
    const int l31  = lane & 31;
    const int hq   = lane >> 5;
    const int bh   = blockIdx.x;
    const int b    = bh >> 4, hh = bh & 15;
    const int iw   = blockIdx.y * 256 + iwv * 64;

    const int srow0 = (lane >> 3);
    const int ssl   = lane & 7;

    short8v qf[2][4];
    #pragma unroll
    for (int ig = 0; ig < 2; ++ig) {
        const unsigned short* qp = Qb + ((size_t)bh * L_ + iw + ig * 32 + l31) * DH_ + hq * 8;
        #pragma unroll
        for (int c = 0; c < 4; ++c) qf[ig][c] = *(const short8v*)(qp + c * 16);
    }

    f32x16 accO[2][2] = {};   // [igroup][dh-half]

#define AO_STAGE(bb, jt)                                                            \
    {                                                                               \
        _Pragma("unroll")                                                           \
        for (int u = 0; u < 2; ++u) {                                               \
            int ch  = iwv * 2 + u;                                                  \
            int row = ch * 8 + srow0;                                               \
            gl_lds16(&Kb[((size_t)bh * L_ + (jt) * 64 + row) * DH_ + ((ssl ^ (row & 7)) << 3)], \
                     &KVa[jh * 2 + (bb)][ch * 512]);                                \
            gl_lds16(&Vt[((size_t)bh * DH_ + row) * L_ + (jt) * 64 + ((ssl ^ (row & 7)) << 3)], \
                     &KVa[4 + jh * 2 + (bb)][ch * 512]);                            \
        }                                                                           \
    }

    AO_STAGE(0, jh * 16 + 0);
    AO_STAGE(1, jh * 16 + 1);
    __syncthreads();
    int cur = 0;

    for (int ltj = 0; ltj < 16; ++ltj) {
        if (ltj < 15) WAITV(4); else WAITV(0);
        SBAR();

        // ---- QK^T (two i-groups share each K-fragment) + T12 P packing ----
        uint4 pa[2][4];
        #pragma unroll
        for (int js = 0; js < 2; ++js) {
            f32x16 as0 = {}, as1 = {};
            __builtin_amdgcn_s_setprio(1);
            #pragma unroll
            for (int c = 0; c < 4; ++c) {
                int krow = js * 32 + l31;
                short8v kfr = *(const short8v*)&KVa[jh * 2 + cur][krow * 64 + (((c * 2 + hq) ^ (krow & 7)) << 3)];
                as0 = MFMA32(kfr, qf[0][c], as0);
                as1 = MFMA32(kfr, qf[1][c], as1);
            }
            __builtin_amdgcn_s_setprio(0);
            #pragma unroll
            for (int ig = 0; ig < 2; ++ig) {
                const f32x16& as = (ig == 0) ? as0 : as1;
                float p[16];
                #pragma unroll
                for (int r = 0; r < 16; ++r) p[r] = __builtin_amdgcn_exp2f(as[r]);

                unsigned P0 = pack2_bf16(p[0], p[1]);
                unsigned P1 = pack2_bf16(p[2], p[3]);
                unsigned Q0 = pack2_bf16(p[4], p[5]);
                unsigned Q1 = pack2_bf16(p[6], p[7]);
                asm("v_permlane32_swap_b32 %0, %1" : "+v"(P0), "+v"(Q0));
                asm("v_permlane32_swap_b32 %0, %1" : "+v"(P1), "+v"(Q1));
                pa[ig][js * 2 + 0] = make_uint4(P0, P1, Q0, Q1);

                unsigned R0 = pack2_bf16(p[8],  p[9]);
                unsigned R1 = pack2_bf16(p[10], p[11]);
                unsigned S0 = pack2_bf16(p[12], p[13]);
                unsigned S1 = pack2_bf16(p[14], p[15]);
                asm("v_permlane32_swap_b32 %0, %1" : "+v"(R0), "+v"(S0));
                asm("v_permlane32_swap_b32 %0, %1" : "+v"(R1), "+v"(S1));
                pa[ig][js * 2 + 1] = make_uint4(R0, R1, S0, S1);
            }
        }

        // ---- O += P · Vt^T (two i-groups share each V-fragment) ----
        __builtin_amdgcn_s_setprio(1);
        #pragma unroll
        for (int c = 0; c < 4; ++c) {
            union { uint4 u; short8v s; } pa0, pa1;
            pa0.u = pa[0][c]; pa1.u = pa[1][c];
            int r0 = l31, r1 = 32 + l31;
            short8v vf0 = *(const short8v*)&KVa[4 + jh * 2 + cur][r0 * 64 + (((c * 2 + hq) ^ (r0 & 7)) << 3)];
            short8v vf1 = *(const short8v*)&KVa[4 + jh * 2 + cur][r1 * 64 + (((c * 2 + hq) ^ (r1 & 7)) << 3)];
            accO[0][0] = MFMA32(pa0.s, vf0, accO[0][0]);
            accO[0][1] = MFMA32(pa0.s, vf1, accO[0][1]);
            accO[1][0] = MFMA32(pa1.s, vf0, accO[1][0]);
            accO[1][1] = MFMA32(pa1.s, vf1, accO[1][1]);
        }
        __builtin_amdgcn_s_setprio(0);
        SBAR();
        if (ltj + 2 < 16) AO_STAGE(cur, jh * 16 + ltj + 2);
        cur ^= 1;
    }

    // ---- combine j-halves: REUSE the K/V arena (all reads done at last SBAR).
    float* comb = (float*)&KVa[0][0];            // 4 * 64 * 64 floats = 64KB
    if (jh == 1) {
        float* cb = comb + iwv * 4096 + lane;
        #pragma unroll
        for (int g = 0; g < 2; ++g)
            #pragma unroll
            for (int h = 0; h < 2; ++h)
                #pragma unroll
                for (int r = 0; r < 16; ++r)
                    cb[((g * 2 + h) * 16 + r) * 64] = accO[g][h][r];
    }
    __syncthreads();
    if (jh == 0) {
        const float* cb = comb + iwv * 4096 + lane;
        #pragma unroll
        for (int g = 0; g < 2; ++g)
            #pragma unroll
            for (int h = 0; h < 2; ++h)
                #pragma unroll
                for (int r = 0; r < 16; ++r)
                    accO[g][h][r] += cb[((g * 2 + h) * 16 + r) * 64];

        #pragma unroll
        for (int ig = 0; ig < 2; ++ig) {
            #pragma unroll
            for (int q = 0; q < 4; ++q) {
                float4 xq = *(const float4*)&x[(size_t)b * L_ + iw + ig * 32 + 4 * hq + 8 * q];
                const float xs[4] = { xq.x, xq.y, xq.z, xq.w };
                #pragma unroll
                for (int k = 0; k < 4; ++k) {
                    int r    = q * 4 + k;
                    int irow = iw + ig * 32 + 4 * hq + 8 * q + k;
                    size_t base = ((size_t)b * L_ + irow) * E_ + hh * DH_;
                    Of[base + l31]      = (_Float16)(accO[ig][0][r] * xs[k]);
                    Of[base + 32 + l31] = (_Float16)(accO[ig][1][r] * xs[k]);
                }
            }
        }
    }
#undef AO_STAGE
}

// ---------------------------------------------------------------------------
// Kernel 4: fused MLP, fp16 MFMA, 128x128, BK=64.
// Min-2-phase pipeline: one barrier per K-step. (R19-proven)
// Grid (m=32, n=32); y pre-zeroed; b2 folded at n-block 0.
// ---------------------------------------------------------------------------
__global__ __launch_bounds__(256) void mlp_mfma(
    const _Float16* __restrict__ Of, const _Float16* __restrict__ W1t,
    const float* __restrict__ b1, const float* __restrict__ W2,
    const float* __restrict__ b2, float* __restrict__ y)
{
    __shared__ _Float16 Oh[2][128 * 64];
    __shared__ _Float16 Wh[2][128 * 64];

    const int t    = threadIdx.x;
    const int lane = t & 63;
    const int w    = t >> 6;
    const int l31  = lane & 31;
    const int hq   = lane >> 5;
    const int wm   = w >> 1, wn = w & 1;
    const int m0   = blockIdx.x * 128;
    const int n0   = blockIdx.y * 128;

    const int srow0 = (lane >> 3);
    const int ssl   = lane & 7;

    f32x16 acc[2][2] = {};

#define MLP_STAGE(bb, kc)                                                          \
    {                                                                              \
        _Pragma("unroll")                                                          \
        for (int u = 0; u < 4; ++u) {                                              \
            int ch  = w * 4 + u;                                                   \
            int row = ch * 8 + srow0;                                              \
            gl_lds16(&Of[(size_t)(m0 + row) * E_ + (kc) * 64 + ((ssl ^ (row & 7)) << 3)], \
                     &Oh[bb][ch * 512]);                                           \
            gl_lds16(&W1t[(size_t)(n0 + row) * E_ + (kc) * 64 + ((ssl ^ (row & 7)) << 3)], \
                     &Wh[bb][ch * 512]);                                           \
        }                                                                          \
    }

    MLP_STAGE(0, 0);
    __syncthreads();                 // buf0 staged & drained
    int cur = 0;

    for (int kc = 0; kc < 16; ++kc) {
        if (kc < 15) MLP_STAGE(cur ^ 1, kc + 1);   // issue next tile first
        __builtin_amdgcn_s_setprio(1);
        #pragma unroll
        for (int ks = 0; ks < 4; ++ks) {
            half8v fb[2];
            #pragma unroll
            for (int nb = 0; nb < 2; ++nb) {
                int br = wn * 64 + nb * 32 + l31;
                fb[nb] = *(const half8v*)&Wh[cur][br * 64 + (((ks * 2 + hq) ^ (br & 7)) << 3)];
            }
            #pragma unroll
            for (int mb = 0; mb < 2; ++mb) {
                int ar = wm * 64 + mb * 32 + l31;
                half8v fa = *(const half8v*)&Oh[cur][ar * 64 + (((ks * 2 + hq) ^ (ar & 7)) << 3)];
                acc[mb][0] = MFMAH(fa, fb[0], acc[mb][0]);
                acc[mb][1] = MFMAH(fa, fb[1], acc[mb][1]);
            }
        }
        __builtin_amdgcn_s_setprio(0);
        WAITV(0);                    // next tile landed (covered by MFMA phase)
        SBAR();                      // all waves done reading buf[cur]
        cur ^= 1;
    }

    // epilogue: gelu + W2 dot; reduce over 32 lanes; atomicAdd per row.
    const int hid0 = n0 + wn * 64 + l31;
    const float bb0 = b1[hid0],      w20 = W2[hid0];
    const float bb1 = b1[hid0 + 32], w21 = W2[hid0 + 32];
    const float b2v = (blockIdx.y == 0) ? b2[0] : 0.0f;
    #pragma unroll
    for (int mb = 0; mb < 2; ++mb) {
        #pragma unroll
        for (int r = 0; r < 16; ++r) {
            float h0 = acc[mb][0][r] + bb0;
            float h1 = acc[mb][1][r] + bb1;
            float s  = 0.5f * h0 * (1.0f + erf_fast(h0 * 0.70710678f)) * w20
                     + 0.5f * h1 * (1.0f + erf_fast(h1 * 0.70710678f)) * w21;
            #pragma unroll
            for (int off = 16; off > 0; off >>= 1) s += __shfl_xor(s, off);
            if (l31 == 0) {
                int m = m0 + wm * 64 + mb * 32 + (r & 3) + 8 * (r >> 2) + 4 * hq;
                atomicAdd(&y[m], s + b2v);
            }
        }
    }
#undef MLP_STAGE
}

// ---------------------------------------------------------------------------
extern "C" void kernel_launch(void* const* d_in, const int* in_sizes, int n_in,
                              void* d_out, int out_size, void* d_ws, size_t ws_size,
                              hipStream_t stream)
{
    const float* x  = (const float*)d_in[0];
    const float* z  = (const float*)d_in[1];
    const float* Wq = (const float*)d_in[2];
    const float* bq = (const float*)d_in[3];
    const float* Wk = (const float*)d_in[4];
    const float* bk = (const float*)d_in[5];
    const float* Wv = (const float*)d_in[6];
    const float* bv = (const float*)d_in[7];
    const float* W1 = (const float*)d_in[8];
    const float* b1 = (const float*)d_in[9];
    const float* W2 = (const float*)d_in[10];
    const float* b2 = (const float*)d_in[11];
    float* y = (float*)d_out;

    const size_t NQ = (size_t)BH_ * L_ * DH_;        // 4.19M elems
    unsigned short* p = (unsigned short*)d_ws;
    unsigned short* Qb  = p;  p += NQ;               // Qb|Kb|Vb contiguous
    unsigned short* Kb  = p;  p += NQ;
    unsigned short* Vb  = p;  p += NQ;
    unsigned short* Vt  = p;  p += NQ;
    _Float16* zh  = (_Float16*)p;  p += (size_t)NROW_ * E_;
    _Float16* Tq  = (_Float16*)p;  p += (size_t)E_ * E_;   // Tq|Tk|Tv contiguous
    _Float16* Tk  = (_Float16*)p;  p += (size_t)E_ * E_;
    _Float16* Tv  = (_Float16*)p;  p += (size_t)E_ * E_;
    _Float16* W1t = (_Float16*)p;  p += (size_t)HID_ * E_;
    _Float16* Ofp = (_Float16*)p;  p += (size_t)NROW_ * E_;

    hipMemsetAsync(y, 0, (size_t)out_size * sizeof(float), stream);

    prep_all<<<dim3(3840), 256, 0, stream>>>(
        z, zh, Wq, Wk, Wv, Tq, Tk, Tv, W1, W1t);

    qkv_mfma<<<dim3(3 * E_ / 128, NROW_ / 128), 256, 0, stream>>>(
        zh, Tq, bq, bk, bv, Qb);

    col_stats_vt<<<dim3(BH_, L_ / 256), 512, 0, stream>>>(Qb, Kb, Vb, x, Vt);

    attn_out_mfma<<<dim3(BH_, L_ / 256), 512, 0, stream>>>(Qb, Kb, Vt, x, Ofp);

    mlp_mfma<<<dim3(NROW_ / 128, HID_ / 128), 256, 0, stream>>>(
        Ofp, W1t, b1, W2, b2, y);
}